// Round 1
// baseline (134.087 us; speedup 1.0000x reference)
//
#include <hip/hip_runtime.h>
#include <hip/hip_bf16.h>

// Problem constants
#define BB 32
#define GG 1024
#define VV 10000
#define KHID 1024
#define MM 128

// ---------------------------------------------------------------------------
// K1: T = allDBGEmb @ W_fc[HID:2*HID, :]   ([10000,1024] @ [1024,128])
// split-K = 2: blockIdx.y selects k-half, writes to T0 / T1 (T1 = T0 + VV*MM).
// 64 rows x 128 cols per block, 256 threads, 8x4 register tile per thread.
// ---------------------------------------------------------------------------
__global__ __launch_bounds__(256) void k_gemm(const float* __restrict__ A,
                                              const float* __restrict__ Wfc,
                                              float* __restrict__ Tout) {
    const int ks = blockIdx.y;                  // 0 or 1 (k-split)
    float* T = Tout + (size_t)ks * (VV * MM);
    const float* Wg = Wfc + (size_t)KHID * MM;  // second-half rows of W_fc

    __shared__ float Wt[32][128];   // [kk][m]
    __shared__ float At[32][65];    // [kk][row]  (padded: stride 65 -> conflict-free)

    const int v0  = blockIdx.x * 64;
    const int tid = threadIdx.x;
    const int tm  = tid & 31;       // col group: cols tm*4 .. tm*4+3
    const int tr  = tid >> 5;       // row group: rows tr*8 .. tr*8+7

    float acc[8][4];
#pragma unroll
    for (int i = 0; i < 8; ++i)
#pragma unroll
        for (int j = 0; j < 4; ++j) acc[i][j] = 0.f;

    const int kbase0 = ks * 512;
    for (int kt = 0; kt < 16; ++kt) {
        const int kb = kbase0 + kt * 32;
        // stage W tile: 32 x 128 = 4096 elements, coalesced
#pragma unroll
        for (int i = 0; i < 16; ++i) {
            int idx = tid + i * 256;
            int kk = idx >> 7, c = idx & 127;
            Wt[kk][c] = Wg[(size_t)(kb + kk) * MM + c];
        }
        // stage A tile transposed: 64 rows x 32 k -> At[kk][row]
#pragma unroll
        for (int i = 0; i < 8; ++i) {
            int idx = tid + i * 256;
            int r = idx >> 5, kk = idx & 31;
            int v = v0 + r;
            At[kk][r] = (v < VV) ? A[(size_t)v * KHID + kb + kk] : 0.f;
        }
        __syncthreads();
#pragma unroll
        for (int kk = 0; kk < 32; ++kk) {
            float4 w  = *(const float4*)&Wt[kk][tm * 4];
            float4 a0 = *(const float4*)&At[kk][tr * 8];
            float4 a1 = *(const float4*)&At[kk][tr * 8 + 4];
            float av[8] = {a0.x, a0.y, a0.z, a0.w, a1.x, a1.y, a1.z, a1.w};
            float wv[4] = {w.x, w.y, w.z, w.w};
#pragma unroll
            for (int i = 0; i < 8; ++i)
#pragma unroll
                for (int j = 0; j < 4; ++j) acc[i][j] += av[i] * wv[j];
        }
        __syncthreads();
    }
#pragma unroll
    for (int i = 0; i < 8; ++i) {
        int v = v0 + tr * 8 + i;
        if (v < VV) {
            float4 o = make_float4(acc[i][0], acc[i][1], acc[i][2], acc[i][3]);
            *(float4*)&T[(size_t)v * MM + tm * 4] = o;
        }
    }
}

// ---------------------------------------------------------------------------
// K2: partial sums for BN stats over G: per (b, chunk of 128 g, m):
//     ps1 = sum T[gPos[b,g],m], ps2 = sum T^2
// ---------------------------------------------------------------------------
__global__ __launch_bounds__(256) void k_stats(const float* __restrict__ T0,
                                               const int* __restrict__ gPos,
                                               float* __restrict__ ps1,
                                               float* __restrict__ ps2) {
    const int b = blockIdx.y, chunk = blockIdx.x;  // 8 chunks of 128 g
    const int tid = threadIdx.x;
    const int m = tid & 127, half = tid >> 7;

    __shared__ int posl[128];
    __shared__ float r1[256], r2[256];

    if (tid < 128) posl[tid] = gPos[b * GG + chunk * 128 + tid];
    __syncthreads();

    float s1 = 0.f, s2 = 0.f;
    for (int g = half; g < 128; g += 2) {
        const float* row = T0 + (size_t)posl[g] * MM;
        float t = row[m] + row[(size_t)VV * MM + m];  // T0 + T1
        s1 += t;
        s2 += t * t;
    }
    r1[tid] = s1;
    r2[tid] = s2;
    __syncthreads();
    if (tid < 128) {
        float S1 = r1[tid] + r1[tid + 128];
        float S2 = r2[tid] + r2[tid + 128];
        ps1[(size_t)(b * 8 + chunk) * MM + m] = S1;
        ps2[(size_t)(b * 8 + chunk) * MM + m] = S2;
    }
}

// ---------------------------------------------------------------------------
// K3: combine partials -> per (b,m) scale/shift for fused BN:
//     scale = gamma * rstd ; shift = beta - scale * mean
// ---------------------------------------------------------------------------
__global__ __launch_bounds__(128) void k_combine(const float* __restrict__ ps1,
                                                 const float* __restrict__ ps2,
                                                 const float* __restrict__ gamma,
                                                 const float* __restrict__ beta,
                                                 float* __restrict__ scale,
                                                 float* __restrict__ shift) {
    const int b = blockIdx.x;
    const int m = threadIdx.x;
    float S1 = 0.f, S2 = 0.f;
    for (int c = 0; c < 8; ++c) {
        S1 += ps1[(size_t)(b * 8 + c) * MM + m];
        S2 += ps2[(size_t)(b * 8 + c) * MM + m];
    }
    float mean = S1 * (1.f / 1024.f);
    float var  = S2 * (1.f / 1024.f) - mean * mean;
    float rstd = rsqrtf(var + 1e-5f);
    float sc = gamma[m] * rstd;
    scale[b * MM + m] = sc;
    shift[b * MM + m] = beta[m] - sc * mean;
}

// ---------------------------------------------------------------------------
// K4: final: out[b,g] = sigmoid( sum_m relu(scale*T+shift) * W2[m] + b2 )
// one wave per (b,g) iteration; lane covers m and m+64; shuffle-reduce.
// ---------------------------------------------------------------------------
__global__ __launch_bounds__(256) void k_final(const float* __restrict__ T0,
                                               const int* __restrict__ gPos,
                                               const float* __restrict__ scale,
                                               const float* __restrict__ shift,
                                               const float* __restrict__ W2,
                                               const float* __restrict__ b2,
                                               float* __restrict__ out) {
    const int b = blockIdx.y, gc = blockIdx.x;  // 8 chunks of 128 g
    const int tid = threadIdx.x;
    const int wave = tid >> 6, lane = tid & 63;
    const int m0 = lane, m1 = lane + 64;

    const float sc0 = scale[b * MM + m0], sh0 = shift[b * MM + m0], w20 = W2[m0];
    const float sc1 = scale[b * MM + m1], sh1 = shift[b * MM + m1], w21 = W2[m1];
    const float bias = b2[0];

    const int gbase = gc * 128 + wave * 32;
    for (int i = 0; i < 32; ++i) {
        int g = gbase + i;
        int pos = gPos[b * GG + g];
        const float* row = T0 + (size_t)pos * MM;
        float t0 = row[m0] + row[(size_t)VV * MM + m0];
        float t1 = row[m1] + row[(size_t)VV * MM + m1];
        float h0 = fmaxf(sc0 * t0 + sh0, 0.f);
        float h1 = fmaxf(sc1 * t1 + sh1, 0.f);
        float val = h0 * w20 + h1 * w21;
#pragma unroll
        for (int off = 32; off; off >>= 1) val += __shfl_xor(val, off, 64);
        if (lane == 0) out[b * GG + g] = 1.f / (1.f + __expf(-(val + bias)));
    }
}

// ---------------------------------------------------------------------------
extern "C" void kernel_launch(void* const* d_in, const int* in_sizes, int n_in,
                              void* d_out, int out_size, void* d_ws, size_t ws_size,
                              hipStream_t stream) {
    // input order per setup_inputs():
    // 0 h, 1 edge_src, 2 edge_dst, 3 gPos, 4 allDBGEmb, 5 W_init, 6 b_init,
    // 7 gamma1, 8 beta1, 9 gamma2, 10 beta2, 11 W_fc, 12 b_fc,
    // 13 gamma_bn, 14 beta_bn, 15 W_fc2, 16 b_fc2
    const int*   gPos  = (const int*)d_in[3];
    const float* A     = (const float*)d_in[4];
    const float* Wfc   = (const float*)d_in[11];
    const float* gamma = (const float*)d_in[13];
    const float* beta  = (const float*)d_in[14];
    const float* W2    = (const float*)d_in[15];
    const float* b2    = (const float*)d_in[16];
    float* out = (float*)d_out;

    float* ws    = (float*)d_ws;
    float* T0    = ws;                           // 2 * VV * MM floats (T0 then T1)
    float* ps1   = T0 + (size_t)2 * VV * MM;     // 32*8*128
    float* ps2   = ps1 + BB * 8 * MM;            // 32*8*128
    float* scale = ps2 + BB * 8 * MM;            // 32*128
    float* shift = scale + BB * MM;              // 32*128

    hipLaunchKernelGGL(k_gemm, dim3(157, 2), dim3(256), 0, stream, A, Wfc, T0);
    hipLaunchKernelGGL(k_stats, dim3(8, BB), dim3(256), 0, stream, T0, gPos, ps1, ps2);
    hipLaunchKernelGGL(k_combine, dim3(BB), dim3(128), 0, stream, ps1, ps2, gamma, beta,
                       scale, shift);
    hipLaunchKernelGGL(k_final, dim3(8, BB), dim3(256), 0, stream, T0, gPos, scale, shift,
                       W2, b2, out);
}

// Round 2
// 83.923 us; speedup vs baseline: 1.5977x; 1.5977x over previous
//
#include <hip/hip_runtime.h>
#include <hip/hip_bf16.h>

// Problem constants
#define BB 32
#define GG 1024
#define VV 10000
#define KHID 1024
#define MM 128

typedef __attribute__((ext_vector_type(8))) short short8;
typedef __attribute__((ext_vector_type(4))) float f32x4;

// f32 -> bf16 bits, round-to-nearest-even
__device__ __forceinline__ unsigned short bf16_rne(float f) {
    union { float f; unsigned int u; } v; v.f = f;
    unsigned int r = v.u + 0x7FFFu + ((v.u >> 16) & 1u);
    return (unsigned short)(r >> 16);
}

// ---------------------------------------------------------------------------
// K0: WtB[col][k] = bf16(W_fc[HID + k][col])  (transpose+convert, LDS-tiled)
// grid (16, 4): 64-k x 32-col tiles, 256 threads.
// ---------------------------------------------------------------------------
__global__ __launch_bounds__(256) void k_convW(const float* __restrict__ Wfc,
                                               unsigned short* __restrict__ WtB) {
    __shared__ float Lt[64][33];
    const int k0 = blockIdx.x * 64, c0 = blockIdx.y * 32;
    const int tid = threadIdx.x;
    const float* Wg = Wfc + (size_t)KHID * MM;  // second-half rows of W_fc
#pragma unroll
    for (int i = 0; i < 8; ++i) {
        int idx = tid + i * 256;
        int kk = idx >> 5, c = idx & 31;
        Lt[kk][c] = Wg[(size_t)(k0 + kk) * MM + c0 + c];
    }
    __syncthreads();
#pragma unroll
    for (int i = 0; i < 8; ++i) {
        int idx = tid + i * 256;
        int c = idx >> 6, kk = idx & 63;
        WtB[(size_t)(c0 + c) * KHID + k0 + kk] = bf16_rne(Lt[kk][c]);
    }
}

// ---------------------------------------------------------------------------
// K1: Tpart[ks] = A[:, ks-slab] @ W[ks-slab, :] via bf16 MFMA.
// Block: 256 thr = 4 waves; wave w computes rows v0+w*16..+15 x all 128 cols.
// A frag: lane l = A[row l&15][k0 + (l>>4)*8 .. +7] (f32 load, cvt to bf16).
// B frag: lane l = WtB[col l&15][k0 + (l>>4)*8 .. +7] (bf16x8 direct load).
// ---------------------------------------------------------------------------
template <int KSLAB>
__global__ __launch_bounds__(256) void k_gemm_mfma(const float* __restrict__ A,
                                                   const unsigned short* __restrict__ WtB,
                                                   float* __restrict__ Tpart) {
    const int ks = blockIdx.y;
    const int kbase = ks * KSLAB;
    const int v0 = blockIdx.x * 64;
    const int w = threadIdx.x >> 6, lane = threadIdx.x & 63;
    const int r16 = lane & 15, g = lane >> 4;

    int rowa = v0 + w * 16 + r16;
    if (rowa > VV - 1) rowa = VV - 1;  // clamp loads; stores are guarded
    const float* Ap = A + (size_t)rowa * KHID + kbase + g * 8;
    const unsigned short* Bp = WtB + (size_t)r16 * KHID + kbase + g * 8;

    f32x4 acc[8];
#pragma unroll
    for (int t = 0; t < 8; ++t) acc[t] = (f32x4){0.f, 0.f, 0.f, 0.f};

#pragma unroll
    for (int kt = 0; kt < (KSLAB >> 5); ++kt) {
        float4 a0 = *(const float4*)(Ap + kt * 32);
        float4 a1 = *(const float4*)(Ap + kt * 32 + 4);
        short8 af;
        af[0] = (short)bf16_rne(a0.x); af[1] = (short)bf16_rne(a0.y);
        af[2] = (short)bf16_rne(a0.z); af[3] = (short)bf16_rne(a0.w);
        af[4] = (short)bf16_rne(a1.x); af[5] = (short)bf16_rne(a1.y);
        af[6] = (short)bf16_rne(a1.z); af[7] = (short)bf16_rne(a1.w);
#pragma unroll
        for (int t = 0; t < 8; ++t) {
            short8 bf = *(const short8*)(Bp + (size_t)t * 16 * KHID + kt * 32);
            acc[t] = __builtin_amdgcn_mfma_f32_16x16x32_bf16(af, bf, acc[t], 0, 0, 0);
        }
    }

    float* Tp = Tpart + (size_t)ks * (VV * MM);
    const int rowbase = v0 + w * 16 + g * 4;
#pragma unroll
    for (int t = 0; t < 8; ++t)
#pragma unroll
        for (int r = 0; r < 4; ++r) {
            int row = rowbase + r;
            if (row < VV) Tp[(size_t)row * MM + t * 16 + r16] = acc[t][r];
        }
}

// ---------------------------------------------------------------------------
// K2: in-place split-K reduce: slab0[i] = sum_s slab_s[i]. Race-free (each
// thread owns one float4 index). T final = ws base (slab 0).
// ---------------------------------------------------------------------------
__global__ __launch_bounds__(256) void k_reduce(float* __restrict__ Tpart, int nslab) {
    size_t i = ((size_t)blockIdx.x * 256 + threadIdx.x) * 4;
    float4 s = *(const float4*)(Tpart + i);
    for (int sl = 1; sl < nslab; ++sl) {
        float4 p = *(const float4*)(Tpart + (size_t)sl * (VV * MM) + i);
        s.x += p.x; s.y += p.y; s.z += p.z; s.w += p.w;
    }
    *(float4*)(Tpart + i) = s;
}

// ---------------------------------------------------------------------------
// K3: partial BN stats over G per (b, chunk of 128 g, m)
// ---------------------------------------------------------------------------
__global__ __launch_bounds__(256) void k_stats(const float* __restrict__ T0,
                                               const int* __restrict__ gPos,
                                               float* __restrict__ ps1,
                                               float* __restrict__ ps2) {
    const int b = blockIdx.y, chunk = blockIdx.x;
    const int tid = threadIdx.x;
    const int m = tid & 127, half = tid >> 7;

    __shared__ int posl[128];
    __shared__ float r1[256], r2[256];

    if (tid < 128) posl[tid] = gPos[b * GG + chunk * 128 + tid];
    __syncthreads();

    float s1 = 0.f, s2 = 0.f;
    for (int g = half; g < 128; g += 2) {
        float t = T0[(size_t)posl[g] * MM + m];
        s1 += t;
        s2 += t * t;
    }
    r1[tid] = s1;
    r2[tid] = s2;
    __syncthreads();
    if (tid < 128) {
        ps1[(size_t)(b * 8 + chunk) * MM + m] = r1[tid] + r1[tid + 128];
        ps2[(size_t)(b * 8 + chunk) * MM + m] = r2[tid] + r2[tid + 128];
    }
}

// ---------------------------------------------------------------------------
// K4: combine partials -> scale/shift per (b,m)
// ---------------------------------------------------------------------------
__global__ __launch_bounds__(128) void k_combine(const float* __restrict__ ps1,
                                                 const float* __restrict__ ps2,
                                                 const float* __restrict__ gamma,
                                                 const float* __restrict__ beta,
                                                 float* __restrict__ scale,
                                                 float* __restrict__ shift) {
    const int b = blockIdx.x;
    const int m = threadIdx.x;
    float S1 = 0.f, S2 = 0.f;
    for (int c = 0; c < 8; ++c) {
        S1 += ps1[(size_t)(b * 8 + c) * MM + m];
        S2 += ps2[(size_t)(b * 8 + c) * MM + m];
    }
    float mean = S1 * (1.f / 1024.f);
    float var  = S2 * (1.f / 1024.f) - mean * mean;
    float rstd = rsqrtf(var + 1e-5f);
    float sc = gamma[m] * rstd;
    scale[b * MM + m] = sc;
    shift[b * MM + m] = beta[m] - sc * mean;
}

// ---------------------------------------------------------------------------
// K5: out[b,g] = sigmoid( sum_m relu(scale*T+shift) * W2[m] + b2 )
// ---------------------------------------------------------------------------
__global__ __launch_bounds__(256) void k_final(const float* __restrict__ T0,
                                               const int* __restrict__ gPos,
                                               const float* __restrict__ scale,
                                               const float* __restrict__ shift,
                                               const float* __restrict__ W2,
                                               const float* __restrict__ b2,
                                               float* __restrict__ out) {
    const int b = blockIdx.y, gc = blockIdx.x;
    const int tid = threadIdx.x;
    const int wave = tid >> 6, lane = tid & 63;
    const int m0 = lane, m1 = lane + 64;

    const float sc0 = scale[b * MM + m0], sh0 = shift[b * MM + m0], w20 = W2[m0];
    const float sc1 = scale[b * MM + m1], sh1 = shift[b * MM + m1], w21 = W2[m1];
    const float bias = b2[0];

    const int gbase = gc * 128 + wave * 32;
    for (int i = 0; i < 32; ++i) {
        int g = gbase + i;
        int pos = gPos[b * GG + g];
        const float* row = T0 + (size_t)pos * MM;
        float t0 = row[m0];
        float t1 = row[m1];
        float h0 = fmaxf(sc0 * t0 + sh0, 0.f);
        float h1 = fmaxf(sc1 * t1 + sh1, 0.f);
        float val = h0 * w20 + h1 * w21;
#pragma unroll
        for (int off = 32; off; off >>= 1) val += __shfl_xor(val, off, 64);
        if (lane == 0) out[b * GG + g] = 1.f / (1.f + __expf(-(val + bias)));
    }
}

// ---------------------------------------------------------------------------
extern "C" void kernel_launch(void* const* d_in, const int* in_sizes, int n_in,
                              void* d_out, int out_size, void* d_ws, size_t ws_size,
                              hipStream_t stream) {
    const int*   gPos  = (const int*)d_in[3];
    const float* A     = (const float*)d_in[4];
    const float* Wfc   = (const float*)d_in[11];
    const float* gamma = (const float*)d_in[13];
    const float* beta  = (const float*)d_in[14];
    const float* W2    = (const float*)d_in[15];
    const float* b2    = (const float*)d_in[16];
    float* out = (float*)d_out;

    const size_t slabB = (size_t)VV * MM * sizeof(float);       // 5.12 MB
    const size_t tailB = 256 * 1024 /*WtB*/ + 2 * 131072 /*ps*/ + 2 * 16384 /*sc/sh*/;
    // split-K chosen from available scratch; constant across calls -> deterministic
    const int SPLIT = (ws_size >= 4 * slabB + tailB) ? 4 : 2;

    float* Tpart = (float*)d_ws;                       // SPLIT slabs; slab0 = final T
    unsigned short* WtB = (unsigned short*)((char*)d_ws + SPLIT * slabB);
    float* ps1   = (float*)((char*)WtB + 256 * 1024);
    float* ps2   = ps1 + BB * 8 * MM;
    float* scale = ps2 + BB * 8 * MM;
    float* shift = scale + BB * MM;

    hipLaunchKernelGGL(k_convW, dim3(16, 4), dim3(256), 0, stream, Wfc, WtB);
    if (SPLIT == 4)
        hipLaunchKernelGGL(HIP_KERNEL_NAME(k_gemm_mfma<256>), dim3(157, 4), dim3(256), 0,
                           stream, A, WtB, Tpart);
    else
        hipLaunchKernelGGL(HIP_KERNEL_NAME(k_gemm_mfma<512>), dim3(157, 2), dim3(256), 0,
                           stream, A, WtB, Tpart);
    hipLaunchKernelGGL(k_reduce, dim3(1250), dim3(256), 0, stream, Tpart, SPLIT);
    hipLaunchKernelGGL(k_stats, dim3(8, BB), dim3(256), 0, stream, Tpart, gPos, ps1, ps2);
    hipLaunchKernelGGL(k_combine, dim3(BB), dim3(128), 0, stream, ps1, ps2, gamma, beta,
                       scale, shift);
    hipLaunchKernelGGL(k_final, dim3(8, BB), dim3(256), 0, stream, Tpart, gPos, scale, shift,
                       W2, b2, out);
}

// Round 3
// 64.491 us; speedup vs baseline: 2.0792x; 1.3013x over previous
//
#include <hip/hip_runtime.h>
#include <hip/hip_bf16.h>

// Problem constants
#define BB 32
#define GG 1024
#define VV 10000
#define KHID 1024
#define MM 128

typedef __attribute__((ext_vector_type(8))) short short8;
typedef __attribute__((ext_vector_type(4))) float f32x4;

// f32 -> bf16 bits, round-to-nearest-even
__device__ __forceinline__ unsigned short bf16_rne(float f) {
    union { float f; unsigned int u; } v; v.f = f;
    unsigned int r = v.u + 0x7FFFu + ((v.u >> 16) & 1u);
    return (unsigned short)(r >> 16);
}

// ---------------------------------------------------------------------------
// K0: WtB[col][k] = bf16(W_fc[HID + k][col])  (transpose+convert, LDS-tiled)
// grid (16, 4): 64-k x 32-col tiles, 256 threads.
// ---------------------------------------------------------------------------
__global__ __launch_bounds__(256) void k_convW(const float* __restrict__ Wfc,
                                               unsigned short* __restrict__ WtB) {
    __shared__ float Lt[64][33];
    const int k0 = blockIdx.x * 64, c0 = blockIdx.y * 32;
    const int tid = threadIdx.x;
    const float* Wg = Wfc + (size_t)KHID * MM;  // second-half rows of W_fc
#pragma unroll
    for (int i = 0; i < 8; ++i) {
        int idx = tid + i * 256;
        int kk = idx >> 5, c = idx & 31;
        Lt[kk][c] = Wg[(size_t)(k0 + kk) * MM + c0 + c];
    }
    __syncthreads();
#pragma unroll
    for (int i = 0; i < 8; ++i) {
        int idx = tid + i * 256;
        int c = idx >> 6, kk = idx & 63;
        WtB[(size_t)(c0 + c) * KHID + k0 + kk] = bf16_rne(Lt[kk][c]);
    }
}

// ---------------------------------------------------------------------------
// K1: T = A @ Wg, full K per block. 512 thr = 8 waves; wave w owns K-slab
// [w*128, w*128+128) of the block's 16-row x 128-col output tile.
// Cross-wave accumulation via padded LDS (2-phase), then coalesced f32x4 write.
// 625 blocks x 16 rows = 10000 exactly (no guards).
// ---------------------------------------------------------------------------
__global__ __launch_bounds__(512) void k_gemm(const float* __restrict__ A,
                                              const unsigned short* __restrict__ WtB,
                                              float* __restrict__ T) {
    const int v0 = blockIdx.x * 16;
    const int tid = threadIdx.x;
    const int w = tid >> 6, lane = tid & 63;
    const int r16 = lane & 15, g = lane >> 4;
    const int kbase = w * 128;

    const float* Ap = A + (size_t)(v0 + r16) * KHID + kbase + g * 8;
    const unsigned short* Bp = WtB + (size_t)r16 * KHID + kbase + g * 8;

    f32x4 acc[8];
#pragma unroll
    for (int t = 0; t < 8; ++t) acc[t] = (f32x4){0.f, 0.f, 0.f, 0.f};

#pragma unroll
    for (int kt = 0; kt < 4; ++kt) {
        float4 a0 = *(const float4*)(Ap + kt * 32);
        float4 a1 = *(const float4*)(Ap + kt * 32 + 4);
        short8 af;
        af[0] = (short)bf16_rne(a0.x); af[1] = (short)bf16_rne(a0.y);
        af[2] = (short)bf16_rne(a0.z); af[3] = (short)bf16_rne(a0.w);
        af[4] = (short)bf16_rne(a1.x); af[5] = (short)bf16_rne(a1.y);
        af[6] = (short)bf16_rne(a1.z); af[7] = (short)bf16_rne(a1.w);
#pragma unroll
        for (int t = 0; t < 8; ++t) {
            short8 bf = *(const short8*)(Bp + (size_t)t * 16 * KHID + kt * 32);
            acc[t] = __builtin_amdgcn_mfma_f32_16x16x32_bf16(af, bf, acc[t], 0, 0, 0);
        }
    }

    // cross-wave reduction: 4 slabs, padded inner dim 132 (132 mod 32 = 4 ->
    // +4 rows shifts bank set by 16: 2-way max = free; 16B-aligned rows)
    __shared__ float red[4][16][132];
    if (w >= 4) {
#pragma unroll
        for (int t = 0; t < 8; ++t)
#pragma unroll
            for (int r = 0; r < 4; ++r)
                red[w - 4][g * 4 + r][t * 16 + r16] = acc[t][r];
    }
    __syncthreads();
    if (w < 4) {
#pragma unroll
        for (int t = 0; t < 8; ++t)
#pragma unroll
            for (int r = 0; r < 4; ++r)
                red[w][g * 4 + r][t * 16 + r16] += acc[t][r];
    }
    __syncthreads();

    const int row = tid >> 5, c4 = (tid & 31) * 4;
    float sx[4];
#pragma unroll
    for (int j = 0; j < 4; ++j)
        sx[j] = red[0][row][c4 + j] + red[1][row][c4 + j] +
                red[2][row][c4 + j] + red[3][row][c4 + j];
    *(float4*)&T[(size_t)(v0 + row) * MM + c4] = make_float4(sx[0], sx[1], sx[2], sx[3]);
}

// ---------------------------------------------------------------------------
// K2: partial BN stats over G per (b, chunk of 64 g, m): grid (16, 32)
// ---------------------------------------------------------------------------
__global__ __launch_bounds__(256) void k_stats(const float* __restrict__ T,
                                               const int* __restrict__ gPos,
                                               float* __restrict__ ps1,
                                               float* __restrict__ ps2) {
    const int b = blockIdx.y, chunk = blockIdx.x;
    const int tid = threadIdx.x;
    const int m = tid & 127, half = tid >> 7;

    __shared__ int posl[64];
    __shared__ float r1[256], r2[256];

    if (tid < 64) posl[tid] = gPos[b * GG + chunk * 64 + tid];
    __syncthreads();

    float s1 = 0.f, s2 = 0.f;
    for (int g = half; g < 64; g += 2) {
        float t = T[(size_t)posl[g] * MM + m];
        s1 += t;
        s2 += t * t;
    }
    r1[tid] = s1;
    r2[tid] = s2;
    __syncthreads();
    if (tid < 128) {
        ps1[(size_t)(b * 16 + chunk) * MM + m] = r1[tid] + r1[tid + 128];
        ps2[(size_t)(b * 16 + chunk) * MM + m] = r2[tid] + r2[tid + 128];
    }
}

// ---------------------------------------------------------------------------
// K3: final (combine fused): scale/shift from partials in LDS, then
// out[b,g] = sigmoid( sum_m relu(scale*T+shift) * W2[m] + b2 ).  grid (16,32)
// ---------------------------------------------------------------------------
__global__ __launch_bounds__(256) void k_final(const float* __restrict__ T,
                                               const int* __restrict__ gPos,
                                               const float* __restrict__ ps1,
                                               const float* __restrict__ ps2,
                                               const float* __restrict__ gamma,
                                               const float* __restrict__ beta,
                                               const float* __restrict__ W2,
                                               const float* __restrict__ b2,
                                               float* __restrict__ out) {
    const int b = blockIdx.y, gc = blockIdx.x;
    const int tid = threadIdx.x;

    __shared__ float ssc[128], ssh[128];
    if (tid < 128) {
        float S1 = 0.f, S2 = 0.f;
#pragma unroll
        for (int c = 0; c < 16; ++c) {
            S1 += ps1[(size_t)(b * 16 + c) * MM + tid];
            S2 += ps2[(size_t)(b * 16 + c) * MM + tid];
        }
        float mean = S1 * (1.f / 1024.f);
        float var  = S2 * (1.f / 1024.f) - mean * mean;
        float rstd = rsqrtf(var + 1e-5f);
        float sc = gamma[tid] * rstd;
        ssc[tid] = sc;
        ssh[tid] = beta[tid] - sc * mean;
    }
    __syncthreads();

    const int wave = tid >> 6, lane = tid & 63;
    const int m0 = lane, m1 = lane + 64;
    const float sc0 = ssc[m0], sh0 = ssh[m0], w20 = W2[m0];
    const float sc1 = ssc[m1], sh1 = ssh[m1], w21 = W2[m1];
    const float bias = b2[0];

    const int gbase = gc * 64 + wave * 16;
    for (int i = 0; i < 16; ++i) {
        int g = gbase + i;
        int pos = gPos[b * GG + g];
        const float* row = T + (size_t)pos * MM;
        float t0 = row[m0];
        float t1 = row[m1];
        float h0 = fmaxf(sc0 * t0 + sh0, 0.f);
        float h1 = fmaxf(sc1 * t1 + sh1, 0.f);
        float val = h0 * w20 + h1 * w21;
#pragma unroll
        for (int off = 32; off; off >>= 1) val += __shfl_xor(val, off, 64);
        if (lane == 0) out[b * GG + g] = 1.f / (1.f + __expf(-(val + bias)));
    }
}

// ---------------------------------------------------------------------------
extern "C" void kernel_launch(void* const* d_in, const int* in_sizes, int n_in,
                              void* d_out, int out_size, void* d_ws, size_t ws_size,
                              hipStream_t stream) {
    const int*   gPos  = (const int*)d_in[3];
    const float* A     = (const float*)d_in[4];
    const float* Wfc   = (const float*)d_in[11];
    const float* gamma = (const float*)d_in[13];
    const float* beta  = (const float*)d_in[14];
    const float* W2    = (const float*)d_in[15];
    const float* b2    = (const float*)d_in[16];
    float* out = (float*)d_out;

    float* ws  = (float*)d_ws;
    float* T   = ws;                                  // VV*MM f32 = 5.12 MB
    unsigned short* WtB = (unsigned short*)(ws + (size_t)VV * MM);  // 256 KB
    float* ps1 = ws + (size_t)VV * MM + 65536;        // 32*16*128 f32
    float* ps2 = ps1 + BB * 16 * MM;

    hipLaunchKernelGGL(k_convW, dim3(16, 4), dim3(256), 0, stream, Wfc, WtB);
    hipLaunchKernelGGL(k_gemm, dim3(625), dim3(512), 0, stream, A, WtB, T);
    hipLaunchKernelGGL(k_stats, dim3(16, BB), dim3(256), 0, stream, T, gPos, ps1, ps2);
    hipLaunchKernelGGL(k_final, dim3(16, BB), dim3(256), 0, stream, T, gPos, ps1, ps2,
                       gamma, beta, W2, b2, out);
}